// Round 4
// baseline (304.591 us; speedup 1.0000x reference)
//
#include <hip/hip_runtime.h>

#define NEG_SLOPE 0.2f
#define NBUCK 1024          // coarse buckets, 128 nodes each (supports n <= 131072)

static __device__ __forceinline__ float lrelu(float x) { return x > 0.f ? x : NEG_SLOPE * x; }

static __device__ __forceinline__ float b2f(unsigned short u) {
    union { unsigned int i; float f; } c; c.i = ((unsigned int)u) << 16; return c.f;
}
static __device__ __forceinline__ unsigned short f2b(float f) {
    union { float f; unsigned int i; } c; c.f = f;
    unsigned int r = c.i + 0x7fff + ((c.i >> 16) & 1);   // RNE
    return (unsigned short)(r >> 16);
}

// ---------------- CSR build: two-level bucket sort ----------------

__global__ __launch_bounds__(256) void bucket_count(const int* __restrict__ dst, int* __restrict__ gcount,
                                                    int ne, int epb) {
    __shared__ int cnt[NBUCK];
    int tid = threadIdx.x;
    for (int i = tid; i < NBUCK; i += 256) cnt[i] = 0;
    __syncthreads();
    int lo = blockIdx.x * epb;
    int hi = min(ne, lo + epb);
    for (int i = lo + tid; i < hi; i += 256) atomicAdd(&cnt[dst[i] >> 7], 1);
    __syncthreads();
    for (int i = tid; i < NBUCK; i += 256) if (cnt[i]) atomicAdd(&gcount[i], cnt[i]);
}

__global__ __launch_bounds__(1024) void bucket_scan(const int* __restrict__ gcount, int* __restrict__ bstart,
                                                    int* __restrict__ gcur) {
    int t = threadIdx.x;
    int v = gcount[t];
    int lane = t & 63, wid = t >> 6;     // 16 waves
    int incl = v;
    #pragma unroll
    for (int off = 1; off < 64; off <<= 1) {
        int u = __shfl_up(incl, off, 64);
        if (lane >= off) incl += u;
    }
    __shared__ int ws[16];
    if (lane == 63) ws[wid] = incl;
    __syncthreads();
    if (t < 16) {
        int s = ws[t];
        #pragma unroll
        for (int off = 1; off < 16; off <<= 1) {
            int u = __shfl_up(s, off, 64);
            if (t >= off) s += u;
        }
        ws[t] = s;
    }
    __syncthreads();
    int excl = incl - v + (wid > 0 ? ws[wid - 1] : 0);
    bstart[t] = excl;
    gcur[t] = excl;
    if (t == 1023) bstart[NBUCK] = excl + v;   // == ne
}

__global__ __launch_bounds__(256) void bucket_place(const int* __restrict__ src, const int* __restrict__ dst,
                                                    int* __restrict__ gcur, unsigned int* __restrict__ gstage,
                                                    int ne, int epb) {
    __shared__ int cnt[NBUCK];
    __shared__ int cur[NBUCK];
    int tid = threadIdx.x;
    for (int i = tid; i < NBUCK; i += 256) cnt[i] = 0;
    __syncthreads();
    int lo = blockIdx.x * epb;
    int hi = min(ne, lo + epb);
    for (int i = lo + tid; i < hi; i += 256) atomicAdd(&cnt[dst[i] >> 7], 1);
    __syncthreads();
    for (int b = tid; b < NBUCK; b += 256) {
        int c = cnt[b];
        cur[b] = c ? atomicAdd(&gcur[b], c) : 0;
    }
    __syncthreads();
    for (int i = lo + tid; i < hi; i += 256) {
        int d = dst[i];
        int b = d >> 7;
        int p = atomicAdd(&cur[b], 1);               // cur holds GLOBAL base
        gstage[p] = (unsigned int)src[i] | (((unsigned int)(d & 127)) << 17);
    }
}

__global__ __launch_bounds__(256) void bucket_csr(const unsigned int* __restrict__ gstage,
                                                  const int* __restrict__ bstart,
                                                  int* __restrict__ rowstart, int* __restrict__ deg,
                                                  int* __restrict__ csrc, int n) {
    int b = blockIdx.x;
    int nodebase = b << 7;
    if (nodebase >= n) return;
    int bs = bstart[b];
    int cntb = bstart[b + 1] - bs;
    __shared__ int hist[128], cur[128], ws[2];
    int tid = threadIdx.x;
    if (tid < 128) hist[tid] = 0;
    __syncthreads();
    for (int i = tid; i < cntb; i += 256) atomicAdd(&hist[(gstage[bs + i] >> 17) & 127], 1);
    __syncthreads();
    int v = 0, incl = 0;
    int lane = tid & 63, wid = tid >> 6;
    if (tid < 128) {
        v = hist[tid];
        incl = v;
        #pragma unroll
        for (int off = 1; off < 64; off <<= 1) {
            int u = __shfl_up(incl, off, 64);
            if (lane >= off) incl += u;
        }
        if (lane == 63) ws[wid] = incl;
    }
    __syncthreads();
    if (tid < 128) {
        int excl = incl - v + (wid == 1 ? ws[0] : 0);
        int node = nodebase + tid;
        if (node < n) { rowstart[node] = bs + excl; deg[node] = v; }
        cur[tid] = excl;
    }
    __syncthreads();
    for (int i = tid; i < cntb; i += 256) {
        unsigned int e = gstage[bs + i];
        int ld = (e >> 17) & 127;
        int p = atomicAdd(&cur[ld], 1);
        csrc[bs + p] = (int)(e & 0x1FFFFu);
    }
}

// ---------------- attention weights: one THREAD per node, exact softmax ----------------

__global__ __launch_bounds__(256) void attn_prep(const float* __restrict__ es, const float* __restrict__ ed,
                                                 const int* __restrict__ rowstart, const int* __restrict__ deg,
                                                 const int* __restrict__ csrc, float* __restrict__ alpha,
                                                 float* __restrict__ aself, int n) {
    int node = blockIdx.x * 256 + threadIdx.x;
    if (node >= n) return;
    float edn = ed[node];
    float e0 = lrelu(es[node] + edn);   // self-loop
    float m = e0, z = 1.f;
    int s0 = rowstart[node], cnt = deg[node];
    for (int i = 0; i < cnt; ++i) {
        int s = csrc[s0 + i];
        float e = lrelu(es[s] + edn);
        alpha[s0 + i] = e;               // stash raw e
        float mn = fmaxf(m, e);
        z = z * __expf(m - mn) + __expf(e - mn);
        m = mn;
    }
    float zi = 1.f / z;
    aself[node] = __expf(e0 - m) * zi;
    for (int i = 0; i < cnt; ++i)
        alpha[s0 + i] = __expf(alpha[s0 + i] - m) * zi;
}

// ---------------- Layer 1: h1 = x @ W1, bf16 out; W1 column in 128 VGPRs ----------------

__global__ __launch_bounds__(256) void gemm1(const float* __restrict__ x, const float* __restrict__ W1,
                                             const float* __restrict__ asrc, const float* __restrict__ adst,
                                             unsigned short* __restrict__ h, float* __restrict__ es,
                                             float* __restrict__ ed, int n) {
    __shared__ float xl[32][128];   // 16 KB
    int tid = threadIdx.x;
    int lane = tid & 63, wid = tid >> 6;
    float w[128];
    #pragma unroll
    for (int k = 0; k < 128; ++k) w[k] = W1[k * 64 + lane];
    int base = blockIdx.x * 32;
    for (int i = tid; i < 32 * 32; i += 256) {
        int r = i >> 5, c4 = i & 31;
        int nidx = base + r;
        float4 v = make_float4(0.f, 0.f, 0.f, 0.f);
        if (nidx < n) v = *(const float4*)&x[(size_t)nidx * 128 + c4 * 4];
        *(float4*)&xl[r][c4 * 4] = v;
    }
    __syncthreads();
    float as_ = asrc[lane], ad_ = adst[lane];
    for (int r = wid; r < 32; r += 4) {
        int nidx = base + r;
        if (nidx >= n) break;
        float acc = 0.f;
        #pragma unroll
        for (int kk = 0; kk < 32; ++kk) {
            float4 xv = *(const float4*)&xl[r][kk * 4];
            acc = fmaf(xv.x, w[4 * kk + 0], acc);
            acc = fmaf(xv.y, w[4 * kk + 1], acc);
            acc = fmaf(xv.z, w[4 * kk + 2], acc);
            acc = fmaf(xv.w, w[4 * kk + 3], acc);
        }
        h[(size_t)nidx * 64 + lane] = f2b(acc);
        float s = acc * as_, d = acc * ad_;
        #pragma unroll
        for (int off = 32; off >= 1; off >>= 1) {
            s += __shfl_xor(s, off, 64);
            d += __shfl_xor(d, off, 64);
        }
        if (lane == 0) { es[nidx] = s; ed[nidx] = d; }
    }
}

// ---------------- Layer 1 gather: acc += alpha * h[src], ILP-8 ----------------

__global__ __launch_bounds__(256) void gather1(const unsigned short* __restrict__ h, const float* __restrict__ alpha,
                                               const float* __restrict__ aself, const float* __restrict__ b1,
                                               const int* __restrict__ rowstart, const int* __restrict__ deg,
                                               const int* __restrict__ csrc, unsigned short* __restrict__ out, int n) {
    int wid = threadIdx.x >> 6, lane = threadIdx.x & 63;
    int node = blockIdx.x * 4 + wid;
    if (node >= n) return;
    float acc = aself[node] * b2f(h[(size_t)node * 64 + lane]);
    int s0 = rowstart[node], cnt = deg[node];
    int i = 0;
    for (; i + 8 <= cnt; i += 8) {
        int s[8]; float a[8]; float hv[8];
        #pragma unroll
        for (int k = 0; k < 8; ++k) { s[k] = csrc[s0 + i + k]; a[k] = alpha[s0 + i + k]; }
        #pragma unroll
        for (int k = 0; k < 8; ++k) hv[k] = b2f(h[(size_t)s[k] * 64 + lane]);
        #pragma unroll
        for (int k = 0; k < 8; ++k) acc = fmaf(hv[k], a[k], acc);
    }
    for (; i + 4 <= cnt; i += 4) {
        int s[4]; float a[4]; float hv[4];
        #pragma unroll
        for (int k = 0; k < 4; ++k) { s[k] = csrc[s0 + i + k]; a[k] = alpha[s0 + i + k]; }
        #pragma unroll
        for (int k = 0; k < 4; ++k) hv[k] = b2f(h[(size_t)s[k] * 64 + lane]);
        #pragma unroll
        for (int k = 0; k < 4; ++k) acc = fmaf(hv[k], a[k], acc);
    }
    for (; i < cnt; ++i) {
        int s = csrc[s0 + i];
        acc = fmaf(b2f(h[(size_t)s * 64 + lane]), alpha[s0 + i], acc);
    }
    float o = acc + b1[lane];
    out[(size_t)node * 64 + lane] = f2b(o > 0.f ? o : 0.f);   // fused ReLU, bf16
}

// ---------------- Layer 2: h2 = hr @ W2, bf16 in/out; W2 column in 64 VGPRs ----------------

__global__ __launch_bounds__(256) void gemm2(const unsigned short* __restrict__ hin, const float* __restrict__ W2,
                                             const float* __restrict__ asrc, const float* __restrict__ adst,
                                             unsigned short* __restrict__ h2, float* __restrict__ es,
                                             float* __restrict__ ed, int n) {
    __shared__ float xl[16][64];   // 4 KB
    int tid = threadIdx.x;
    int lane = tid & 63, wid = tid >> 6;
    int sub = lane >> 4, j = lane & 15;
    float w2[64];
    #pragma unroll
    for (int k = 0; k < 64; ++k) w2[k] = W2[k * 16 + j];
    int base = blockIdx.x * 16;
    for (int i = tid; i < 16 * 64; i += 256) {
        int r = i >> 6, c = i & 63;
        int nidx = base + r;
        xl[r][c] = (nidx < n) ? b2f(hin[(size_t)nidx * 64 + c]) : 0.f;
    }
    __syncthreads();
    int r = wid * 4 + sub;
    int nidx = base + r;
    if (nidx < n) {
        float acc = 0.f;
        #pragma unroll
        for (int kk = 0; kk < 16; ++kk) {
            float4 xv = *(const float4*)&xl[r][kk * 4];
            acc = fmaf(xv.x, w2[4 * kk + 0], acc);
            acc = fmaf(xv.y, w2[4 * kk + 1], acc);
            acc = fmaf(xv.z, w2[4 * kk + 2], acc);
            acc = fmaf(xv.w, w2[4 * kk + 3], acc);
        }
        h2[(size_t)nidx * 16 + j] = f2b(acc);
        float s = acc * asrc[j], d = acc * adst[j];
        #pragma unroll
        for (int off = 8; off >= 1; off >>= 1) {
            s += __shfl_xor(s, off, 64);
            d += __shfl_xor(d, off, 64);
        }
        if (j == 0) { es[nidx] = s; ed[nidx] = d; }
    }
}

// ---------------- Layer 2 gather + bias + log_softmax ----------------
// wave per node: 4 subgroups of 16 lanes each take every 4th edge; plain add-merge.

__global__ __launch_bounds__(256) void gather2(const unsigned short* __restrict__ h, const float* __restrict__ alpha,
                                               const float* __restrict__ aself, const float* __restrict__ b2,
                                               const int* __restrict__ rowstart, const int* __restrict__ deg,
                                               const int* __restrict__ csrc, float* __restrict__ out, int n) {
    int wid = threadIdx.x >> 6, lane = threadIdx.x & 63;
    int node = blockIdx.x * 4 + wid;
    if (node >= n) return;
    int sub = lane >> 4, j = lane & 15;
    int s0 = rowstart[node], cnt = deg[node];
    float acc = (sub == 0) ? aself[node] * b2f(h[(size_t)node * 16 + j]) : 0.f;
    int i = sub;
    for (; i + 4 < cnt; i += 8) {
        int sA = csrc[s0 + i], sB = csrc[s0 + i + 4];
        float aA = alpha[s0 + i], aB = alpha[s0 + i + 4];
        float hA = b2f(h[(size_t)sA * 16 + j]);
        float hB = b2f(h[(size_t)sB * 16 + j]);
        acc = fmaf(hA, aA, acc);
        acc = fmaf(hB, aB, acc);
    }
    if (i < cnt) {
        int s = csrc[s0 + i];
        acc = fmaf(b2f(h[(size_t)s * 16 + j]), alpha[s0 + i], acc);
    }
    // merge the 4 subgroup partial sums
    acc += __shfl_xor(acc, 16, 64);
    acc += __shfl_xor(acc, 32, 64);
    float val = acc + b2[j];
    float mx = val;
    #pragma unroll
    for (int off = 8; off >= 1; off >>= 1) mx = fmaxf(mx, __shfl_xor(mx, off, 64));
    float ex = __expf(val - mx);
    float se = ex;
    #pragma unroll
    for (int off = 8; off >= 1; off >>= 1) se += __shfl_xor(se, off, 64);
    float res = val - mx - __logf(se);
    if (sub == 0) out[(size_t)node * 16 + j] = res;
}

// ---------------- launch ----------------

extern "C" void kernel_launch(void* const* d_in, const int* in_sizes, int n_in,
                              void* d_out, int out_size, void* d_ws, size_t ws_size,
                              hipStream_t stream) {
    const float* x   = (const float*)d_in[0];
    const int*   ei  = (const int*)d_in[1];
    const float* W1  = (const float*)d_in[2];
    const float* as1 = (const float*)d_in[3];
    const float* ad1 = (const float*)d_in[4];
    const float* b1  = (const float*)d_in[5];
    const float* W2  = (const float*)d_in[6];
    const float* as2 = (const float*)d_in[7];
    const float* ad2 = (const float*)d_in[8];
    const float* b2  = (const float*)d_in[9];
    int n  = in_sizes[0] / 128;
    int ne = in_sizes[1] / 2;
    const int* srcv = ei;
    const int* dstv = ei + ne;

    char* ws = (char*)d_ws;
    size_t off = 0;
    auto alloc = [&](size_t bytes) -> void* {
        void* p = ws + off;
        off = (off + bytes + 255) & ~(size_t)255;
        return p;
    };
    unsigned short* h1 = (unsigned short*)alloc((size_t)n * 64 * 2);
    unsigned short* hr = (unsigned short*)alloc((size_t)n * 64 * 2);
    unsigned short* h2 = (unsigned short*)alloc((size_t)n * 16 * 2);
    float* es1  = (float*)alloc((size_t)n * 4);
    float* ed1  = (float*)alloc((size_t)n * 4);
    float* es2  = (float*)alloc((size_t)n * 4);
    float* ed2  = (float*)alloc((size_t)n * 4);
    float* alpha = (float*)alloc((size_t)ne * 4);   // reused by both layers
    float* aself = (float*)alloc((size_t)n * 4);    // reused by both layers
    int* deg      = (int*)alloc((size_t)n * 4);
    int* rowstart = (int*)alloc((size_t)n * 4);
    int* bcount   = (int*)alloc((size_t)NBUCK * 4);
    int* bstart   = (int*)alloc((size_t)(NBUCK + 1) * 4);
    int* gcur     = (int*)alloc((size_t)NBUCK * 4);
    unsigned int* gstage = (unsigned int*)alloc((size_t)ne * 4);
    int* csrc     = (int*)alloc((size_t)ne * 4);

    int nblk = 512;
    int epb = (ne + nblk - 1) / nblk;
    hipMemsetAsync(bcount, 0, (size_t)NBUCK * 4, stream);
    bucket_count<<<nblk, 256, 0, stream>>>(dstv, bcount, ne, epb);
    bucket_scan<<<1, 1024, 0, stream>>>(bcount, bstart, gcur);
    bucket_place<<<nblk, 256, 0, stream>>>(srcv, dstv, gcur, gstage, ne, epb);
    bucket_csr<<<NBUCK, 256, 0, stream>>>(gstage, bstart, rowstart, deg, csrc, n);

    gemm1<<<(n + 31) / 32, 256, 0, stream>>>(x, W1, as1, ad1, h1, es1, ed1, n);
    attn_prep<<<(n + 255) / 256, 256, 0, stream>>>(es1, ed1, rowstart, deg, csrc, alpha, aself, n);
    gather1<<<(n + 3) / 4, 256, 0, stream>>>(h1, alpha, aself, b1, rowstart, deg, csrc, hr, n);

    gemm2<<<(n + 15) / 16, 256, 0, stream>>>(hr, W2, as2, ad2, h2, es2, ed2, n);
    attn_prep<<<(n + 255) / 256, 256, 0, stream>>>(es2, ed2, rowstart, deg, csrc, alpha, aself, n);
    gather2<<<(n + 3) / 4, 256, 0, stream>>>(h2, alpha, aself, b2, rowstart, deg, csrc, (float*)d_out, n);
}

// Round 7
// 250.728 us; speedup vs baseline: 1.2148x; 1.2148x over previous
//
#include <hip/hip_runtime.h>

#define NEG_SLOPE 0.2f
#define NBUCK 1024          // coarse buckets, 128 nodes each (supports n <= 131072)

typedef __attribute__((ext_vector_type(8))) short bf16x8;
typedef __attribute__((ext_vector_type(4))) float f32x4;

static __device__ __forceinline__ float lrelu(float x) { return x > 0.f ? x : NEG_SLOPE * x; }

static __device__ __forceinline__ float b2f(unsigned short u) {
    union { unsigned int i; float f; } c; c.i = ((unsigned int)u) << 16; return c.f;
}
static __device__ __forceinline__ unsigned short f2b(float f) {
    union { float f; unsigned int i; } c; c.f = f;
    unsigned int r = c.i + 0x7fff + ((c.i >> 16) & 1);   // RNE
    return (unsigned short)(r >> 16);
}

// ---------------- CSR build: two-level bucket sort ----------------

__global__ __launch_bounds__(256) void bucket_count(const int* __restrict__ dst, int* __restrict__ gcount,
                                                    int ne, int epb) {
    __shared__ int cnt[NBUCK];
    int tid = threadIdx.x;
    for (int i = tid; i < NBUCK; i += 256) cnt[i] = 0;
    __syncthreads();
    int lo = blockIdx.x * epb;
    int hi = min(ne, lo + epb);
    for (int i = lo + tid; i < hi; i += 256) atomicAdd(&cnt[dst[i] >> 7], 1);
    __syncthreads();
    for (int i = tid; i < NBUCK; i += 256) if (cnt[i]) atomicAdd(&gcount[i], cnt[i]);
}

__global__ __launch_bounds__(1024) void bucket_scan(const int* __restrict__ gcount, int* __restrict__ bstart,
                                                    int* __restrict__ gcur) {
    int t = threadIdx.x;
    int v = gcount[t];
    int lane = t & 63, wid = t >> 6;     // 16 waves
    int incl = v;
    #pragma unroll
    for (int off = 1; off < 64; off <<= 1) {
        int u = __shfl_up(incl, off, 64);
        if (lane >= off) incl += u;
    }
    __shared__ int ws[16];
    if (lane == 63) ws[wid] = incl;
    __syncthreads();
    if (t < 16) {
        int s = ws[t];
        #pragma unroll
        for (int off = 1; off < 16; off <<= 1) {
            int u = __shfl_up(s, off, 64);
            if (t >= off) s += u;
        }
        ws[t] = s;
    }
    __syncthreads();
    int excl = incl - v + (wid > 0 ? ws[wid - 1] : 0);
    bstart[t] = excl;
    gcur[t] = excl;
    if (t == 1023) bstart[NBUCK] = excl + v;   // == ne
}

__global__ __launch_bounds__(256) void bucket_place(const int* __restrict__ src, const int* __restrict__ dst,
                                                    int* __restrict__ gcur, unsigned int* __restrict__ gstage,
                                                    int ne, int epb) {
    __shared__ int cnt[NBUCK];
    __shared__ int cur[NBUCK];
    int tid = threadIdx.x;
    for (int i = tid; i < NBUCK; i += 256) cnt[i] = 0;
    __syncthreads();
    int lo = blockIdx.x * epb;
    int hi = min(ne, lo + epb);
    for (int i = lo + tid; i < hi; i += 256) atomicAdd(&cnt[dst[i] >> 7], 1);
    __syncthreads();
    for (int b = tid; b < NBUCK; b += 256) {
        int c = cnt[b];
        cur[b] = c ? atomicAdd(&gcur[b], c) : 0;
    }
    __syncthreads();
    for (int i = lo + tid; i < hi; i += 256) {
        int d = dst[i];
        int b = d >> 7;
        int p = atomicAdd(&cur[b], 1);               // cur holds GLOBAL base
        gstage[p] = (unsigned int)src[i] | (((unsigned int)(d & 127)) << 17);
    }
}

__global__ __launch_bounds__(256) void bucket_csr(const unsigned int* __restrict__ gstage,
                                                  const int* __restrict__ bstart,
                                                  int* __restrict__ rowstart, int* __restrict__ deg,
                                                  int* __restrict__ csrc, int n) {
    int b = blockIdx.x;
    int nodebase = b << 7;
    if (nodebase >= n) return;
    int bs = bstart[b];
    int cntb = bstart[b + 1] - bs;
    __shared__ int hist[128], cur[128], ws[2];
    int tid = threadIdx.x;
    if (tid < 128) hist[tid] = 0;
    __syncthreads();
    for (int i = tid; i < cntb; i += 256) atomicAdd(&hist[(gstage[bs + i] >> 17) & 127], 1);
    __syncthreads();
    int v = 0, incl = 0;
    int lane = tid & 63, wid = tid >> 6;
    if (tid < 128) {
        v = hist[tid];
        incl = v;
        #pragma unroll
        for (int off = 1; off < 64; off <<= 1) {
            int u = __shfl_up(incl, off, 64);
            if (lane >= off) incl += u;
        }
        if (lane == 63) ws[wid] = incl;
    }
    __syncthreads();
    if (tid < 128) {
        int excl = incl - v + (wid == 1 ? ws[0] : 0);
        int node = nodebase + tid;
        if (node < n) { rowstart[node] = bs + excl; deg[node] = v; }
        cur[tid] = excl;
    }
    __syncthreads();
    for (int i = tid; i < cntb; i += 256) {
        unsigned int e = gstage[bs + i];
        int ld = (e >> 17) & 127;
        int p = atomicAdd(&cur[ld], 1);
        csrc[bs + p] = (int)(e & 0x1FFFFu);
    }
}

// ---------------- W1 fragment prep (hi/lo split), one tiny block ----------------

__global__ __launch_bounds__(256) void wprep(const float* __restrict__ W1,
                                             unsigned short* __restrict__ WfH,
                                             unsigned short* __restrict__ WfL) {
    int lane = threadIdx.x & 63, cb = threadIdx.x >> 6;
    int r16 = lane & 15, g4 = lane >> 4;
    for (int kb = 0; kb < 4; ++kb) {
        #pragma unroll
        for (int i = 0; i < 8; ++i) {
            int k = kb * 32 + g4 * 8 + i;
            float v = W1[k * 64 + cb * 16 + r16];
            unsigned short hi = f2b(v);
            unsigned short lo = f2b(v - b2f(hi));
            WfH[((cb * 4 + kb) * 64 + lane) * 8 + i] = hi;
            WfL[((cb * 4 + kb) * 64 + lane) * 8 + i] = lo;
        }
    }
}

// ---------------- Layer 1: h1 = x @ W1 via split-precision bf16 MFMA ----------------
// acc = Ah*Bh + Al*Bh + Ah*Bl (lo*lo dropped) ~= fp32 GEMM.

__global__ __launch_bounds__(256) void gemm1(const float* __restrict__ x,
                                             const unsigned short* __restrict__ WfH,
                                             const unsigned short* __restrict__ WfL,
                                             const float* __restrict__ asrc, const float* __restrict__ adst,
                                             unsigned short* __restrict__ h, float* __restrict__ es,
                                             float* __restrict__ ed, int n) {
    __shared__ unsigned short AsH[64 * 128];   // 16 KB
    __shared__ unsigned short AsL[64 * 128];   // 16 KB
    int tid = threadIdx.x, lane = tid & 63, wid = tid >> 6;
    int r16 = lane & 15, g4 = lane >> 4;

    int base = blockIdx.x * 64;
    #pragma unroll
    for (int jj = 0; jj < 8; ++jj) {
        int idx = tid + jj * 256;          // 0..2047
        int r = idx >> 5, c4 = idx & 31;
        int nidx = base + r;
        float4 v = make_float4(0.f, 0.f, 0.f, 0.f);
        if (nidx < n) v = *(const float4*)&x[(size_t)nidx * 128 + c4 * 4];
        unsigned short h0 = f2b(v.x), h1_ = f2b(v.y), h2_ = f2b(v.z), h3_ = f2b(v.w);
        unsigned short l0 = f2b(v.x - b2f(h0)), l1 = f2b(v.y - b2f(h1_));
        unsigned short l2 = f2b(v.z - b2f(h2_)), l3 = f2b(v.w - b2f(h3_));
        int u = c4 >> 1;
        int swz = (((u ^ (r & 15)) << 1) | (c4 & 1)) << 2;  // shorts offset
        *(unsigned long long*)&AsH[r * 128 + swz] =
            (unsigned long long)h0 | ((unsigned long long)h1_ << 16) |
            ((unsigned long long)h2_ << 32) | ((unsigned long long)h3_ << 48);
        *(unsigned long long*)&AsL[r * 128 + swz] =
            (unsigned long long)l0 | ((unsigned long long)l1 << 16) |
            ((unsigned long long)l2 << 32) | ((unsigned long long)l3 << 48);
    }
    __syncthreads();

    bf16x8 afH[4], afL[4];
    int arow = wid * 16 + r16;
    #pragma unroll
    for (int kb = 0; kb < 4; ++kb) {
        int uu = (kb * 4 + g4) ^ r16;
        afH[kb] = *(const bf16x8*)&AsH[arow * 128 + uu * 8];
        afL[kb] = *(const bf16x8*)&AsL[arow * 128 + uu * 8];
    }

    f32x4 acc[4] = {{0.f,0.f,0.f,0.f},{0.f,0.f,0.f,0.f},{0.f,0.f,0.f,0.f},{0.f,0.f,0.f,0.f}};
    #pragma unroll
    for (int cb = 0; cb < 4; ++cb) {
        #pragma unroll
        for (int kb = 0; kb < 4; ++kb) {
            bf16x8 bH = *(const bf16x8*)&WfH[((cb * 4 + kb) * 64 + lane) * 8];
            bf16x8 bL = *(const bf16x8*)&WfL[((cb * 4 + kb) * 64 + lane) * 8];
            acc[cb] = __builtin_amdgcn_mfma_f32_16x16x32_bf16(afH[kb], bH, acc[cb], 0, 0, 0);
            acc[cb] = __builtin_amdgcn_mfma_f32_16x16x32_bf16(afL[kb], bH, acc[cb], 0, 0, 0);
            acc[cb] = __builtin_amdgcn_mfma_f32_16x16x32_bf16(afH[kb], bL, acc[cb], 0, 0, 0);
        }
    }

    // epilogue: D layout col=lane&15, row=(lane>>4)*4+reg
    float ps[4] = {0.f,0.f,0.f,0.f}, pd[4] = {0.f,0.f,0.f,0.f};
    #pragma unroll
    for (int cb = 0; cb < 4; ++cb) {
        int col = cb * 16 + r16;
        float av = asrc[col], dv = adst[col];
        #pragma unroll
        for (int rg = 0; rg < 4; ++rg) {
            int nidx = base + wid * 16 + g4 * 4 + rg;
            float v = acc[cb][rg];
            if (nidx < n) h[(size_t)nidx * 64 + col] = f2b(v);
            ps[rg] = fmaf(v, av, ps[rg]);
            pd[rg] = fmaf(v, dv, pd[rg]);
        }
    }
    #pragma unroll
    for (int off = 8; off >= 1; off >>= 1) {
        #pragma unroll
        for (int rg = 0; rg < 4; ++rg) {
            ps[rg] += __shfl_xor(ps[rg], off, 64);
            pd[rg] += __shfl_xor(pd[rg], off, 64);
        }
    }
    if (r16 == 0) {
        #pragma unroll
        for (int rg = 0; rg < 4; ++rg) {
            int nidx = base + wid * 16 + g4 * 4 + rg;
            if (nidx < n) { es[nidx] = ps[rg]; ed[nidx] = pd[rg]; }
        }
    }
}

// ---------------- Layer 1 aggregation: wave/node, ILP-4 online softmax (round-3 proven) ----------------

__global__ __launch_bounds__(256) void agg1(const unsigned short* __restrict__ h, const float* __restrict__ es,
                                            const float* __restrict__ ed, const float* __restrict__ b1,
                                            const int* __restrict__ rowstart, const int* __restrict__ deg,
                                            const int* __restrict__ csrc, unsigned short* __restrict__ out, int n) {
    int wid = threadIdx.x >> 6, lane = threadIdx.x & 63;
    int node = blockIdx.x * 4 + wid;
    if (node >= n) return;
    float edn = ed[node];
    float m = lrelu(es[node] + edn);    // self-loop
    float z = 1.0f;
    float acc = b2f(h[(size_t)node * 64 + lane]);
    int s0 = rowstart[node], cnt = deg[node];
    int i = 0;
    for (; i + 4 <= cnt; i += 4) {
        int sA = csrc[s0 + i], sB = csrc[s0 + i + 1], sC = csrc[s0 + i + 2], sD = csrc[s0 + i + 3];
        float eA = lrelu(es[sA] + edn), eB = lrelu(es[sB] + edn);
        float eC = lrelu(es[sC] + edn), eD = lrelu(es[sD] + edn);
        float hA = b2f(h[(size_t)sA * 64 + lane]);
        float hB = b2f(h[(size_t)sB * 64 + lane]);
        float hC = b2f(h[(size_t)sC * 64 + lane]);
        float hD = b2f(h[(size_t)sD * 64 + lane]);
        float mb = fmaxf(fmaxf(eA, eB), fmaxf(eC, eD));
        if (mb <= m) {                       // wave-uniform
            float wA = __expf(eA - m), wB = __expf(eB - m);
            float wC = __expf(eC - m), wD = __expf(eD - m);
            z += (wA + wB) + (wC + wD);
            acc = fmaf(hA, wA, acc);
            acc = fmaf(hB, wB, acc);
            acc = fmaf(hC, wC, acc);
            acc = fmaf(hD, wD, acc);
        } else {
            float c = __expf(m - mb);
            float wA = __expf(eA - mb), wB = __expf(eB - mb);
            float wC = __expf(eC - mb), wD = __expf(eD - mb);
            z = fmaf(z, c, (wA + wB) + (wC + wD));
            acc = acc * c;
            acc = fmaf(hA, wA, acc);
            acc = fmaf(hB, wB, acc);
            acc = fmaf(hC, wC, acc);
            acc = fmaf(hD, wD, acc);
            m = mb;
        }
    }
    for (; i < cnt; ++i) {
        int s = csrc[s0 + i];
        float e = lrelu(es[s] + edn);
        float hv = b2f(h[(size_t)s * 64 + lane]);
        if (e <= m) {
            float w_ = __expf(e - m);
            z += w_;
            acc = fmaf(hv, w_, acc);
        } else {
            float c = __expf(m - e);
            z = fmaf(z, c, 1.0f);
            acc = fmaf(acc, c, hv);
            m = e;
        }
    }
    float o = acc / z + b1[lane];
    out[(size_t)node * 64 + lane] = f2b(o > 0.f ? o : 0.f);   // fused ReLU, bf16
}

// ---------------- Layer 2: h2 = hr @ W2, bf16 in/out; W2 column in 64 VGPRs ----------------

__global__ __launch_bounds__(256) void gemm2(const unsigned short* __restrict__ hin, const float* __restrict__ W2,
                                             const float* __restrict__ asrc, const float* __restrict__ adst,
                                             unsigned short* __restrict__ h2, float* __restrict__ es,
                                             float* __restrict__ ed, int n) {
    __shared__ float xl[16][64];   // 4 KB
    int tid = threadIdx.x;
    int lane = tid & 63, wid = tid >> 6;
    int sub = lane >> 4, j = lane & 15;
    float w2[64];
    #pragma unroll
    for (int k = 0; k < 64; ++k) w2[k] = W2[k * 16 + j];
    int base = blockIdx.x * 16;
    for (int i = tid; i < 16 * 64; i += 256) {
        int r = i >> 6, c = i & 63;
        int nidx = base + r;
        xl[r][c] = (nidx < n) ? b2f(hin[(size_t)nidx * 64 + c]) : 0.f;
    }
    __syncthreads();
    int r = wid * 4 + sub;
    int nidx = base + r;
    if (nidx < n) {
        float acc = 0.f;
        #pragma unroll
        for (int kk = 0; kk < 16; ++kk) {
            float4 xv = *(const float4*)&xl[r][kk * 4];
            acc = fmaf(xv.x, w2[4 * kk + 0], acc);
            acc = fmaf(xv.y, w2[4 * kk + 1], acc);
            acc = fmaf(xv.z, w2[4 * kk + 2], acc);
            acc = fmaf(xv.w, w2[4 * kk + 3], acc);
        }
        h2[(size_t)nidx * 16 + j] = f2b(acc);
        float s = acc * asrc[j], d = acc * adst[j];
        #pragma unroll
        for (int off = 8; off >= 1; off >>= 1) {
            s += __shfl_xor(s, off, 64);
            d += __shfl_xor(d, off, 64);
        }
        if (j == 0) { es[nidx] = s; ed[nidx] = d; }
    }
}

// ---------------- Layer 2 aggregation + bias + log_softmax (round-3 proven) ----------------

__global__ __launch_bounds__(256) void agg2(const unsigned short* __restrict__ h, const float* __restrict__ es,
                                            const float* __restrict__ ed, const float* __restrict__ b2,
                                            const int* __restrict__ rowstart, const int* __restrict__ deg,
                                            const int* __restrict__ csrc, float* __restrict__ out, int n) {
    int wid = threadIdx.x >> 6, lane = threadIdx.x & 63;
    int node = blockIdx.x * 4 + wid;
    if (node >= n) return;
    int sub = lane >> 4, j = lane & 15;
    float edn = ed[node];
    int s0 = rowstart[node], cnt = deg[node];
    int total = cnt + 1;                       // virtual edge 0 = self-loop
    float m = -1e30f, z = 0.f, acc = 0.f;
    for (int i = sub; i < total; i += 4) {
        int s = (i == 0) ? node : csrc[s0 + i - 1];
        float e = lrelu(es[s] + edn);
        float hv = b2f(h[(size_t)s * 16 + j]);
        if (e <= m) {
            float w_ = __expf(e - m);
            z += w_;
            acc = fmaf(hv, w_, acc);
        } else {
            float c = __expf(m - e);
            z = fmaf(z, c, 1.0f);
            acc = fmaf(acc, c, hv);
            m = e;
        }
    }
    #pragma unroll
    for (int off = 16; off <= 32; off <<= 1) {
        float mo = __shfl_xor(m, off, 64);
        float zo = __shfl_xor(z, off, 64);
        float ao = __shfl_xor(acc, off, 64);
        float mn = fmaxf(m, mo);
        float c0 = __expf(m - mn), c1 = __expf(mo - mn);
        z = z * c0 + zo * c1;
        acc = acc * c0 + ao * c1;
        m = mn;
    }
    float val = acc / z + b2[j];
    float mx = val;
    #pragma unroll
    for (int off = 8; off >= 1; off >>= 1) mx = fmaxf(mx, __shfl_xor(mx, off, 64));
    float ex = __expf(val - mx);
    float se = ex;
    #pragma unroll
    for (int off = 8; off >= 1; off >>= 1) se += __shfl_xor(se, off, 64);
    float res = val - mx - __logf(se);
    if (sub == 0) out[(size_t)node * 16 + j] = res;
}

// ---------------- launch ----------------

extern "C" void kernel_launch(void* const* d_in, const int* in_sizes, int n_in,
                              void* d_out, int out_size, void* d_ws, size_t ws_size,
                              hipStream_t stream) {
    const float* x   = (const float*)d_in[0];
    const int*   ei  = (const int*)d_in[1];
    const float* W1  = (const float*)d_in[2];
    const float* as1 = (const float*)d_in[3];
    const float* ad1 = (const float*)d_in[4];
    const float* b1  = (const float*)d_in[5];
    const float* W2  = (const float*)d_in[6];
    const float* as2 = (const float*)d_in[7];
    const float* ad2 = (const float*)d_in[8];
    const float* b2  = (const float*)d_in[9];
    int n  = in_sizes[0] / 128;
    int ne = in_sizes[1] / 2;
    const int* srcv = ei;
    const int* dstv = ei + ne;

    char* ws = (char*)d_ws;
    size_t off = 0;
    auto alloc = [&](size_t bytes) -> void* {
        void* p = ws + off;
        off = (off + bytes + 255) & ~(size_t)255;
        return p;
    };
    unsigned short* h1 = (unsigned short*)alloc((size_t)n * 64 * 2);
    unsigned short* hr = (unsigned short*)alloc((size_t)n * 64 * 2);
    unsigned short* h2 = (unsigned short*)alloc((size_t)n * 16 * 2);
    float* es1  = (float*)alloc((size_t)n * 4);
    float* ed1  = (float*)alloc((size_t)n * 4);
    float* es2  = (float*)alloc((size_t)n * 4);
    float* ed2  = (float*)alloc((size_t)n * 4);
    unsigned short* WfH = (unsigned short*)alloc(16 * 64 * 8 * 2);
    unsigned short* WfL = (unsigned short*)alloc(16 * 64 * 8 * 2);
    int* deg      = (int*)alloc((size_t)n * 4);
    int* rowstart = (int*)alloc((size_t)n * 4);
    int* bcount   = (int*)alloc((size_t)NBUCK * 4);
    int* bstart   = (int*)alloc((size_t)(NBUCK + 1) * 4);
    int* gcur     = (int*)alloc((size_t)NBUCK * 4);
    unsigned int* gstage = (unsigned int*)alloc((size_t)ne * 4);
    int* csrc     = (int*)alloc((size_t)ne * 4);

    int nblk = 512;
    int epb = (ne + nblk - 1) / nblk;
    hipMemsetAsync(bcount, 0, (size_t)NBUCK * 4, stream);
    bucket_count<<<nblk, 256, 0, stream>>>(dstv, bcount, ne, epb);
    bucket_scan<<<1, 1024, 0, stream>>>(bcount, bstart, gcur);
    bucket_place<<<nblk, 256, 0, stream>>>(srcv, dstv, gcur, gstage, ne, epb);
    bucket_csr<<<NBUCK, 256, 0, stream>>>(gstage, bstart, rowstart, deg, csrc, n);

    wprep<<<1, 256, 0, stream>>>(W1, WfH, WfL);
    gemm1<<<(n + 63) / 64, 256, 0, stream>>>(x, WfH, WfL, as1, ad1, h1, es1, ed1, n);
    agg1<<<(n + 3) / 4, 256, 0, stream>>>(h1, es1, ed1, b1, rowstart, deg, csrc, hr, n);

    gemm2<<<(n + 15) / 16, 256, 0, stream>>>(hr, W2, as2, ad2, h2, es2, ed2, n);
    agg2<<<(n + 3) / 4, 256, 0, stream>>>(h2, es2, ed2, b2, rowstart, deg, csrc, (float*)d_out, n);
}

// Round 8
// 243.793 us; speedup vs baseline: 1.2494x; 1.0284x over previous
//
#include <hip/hip_runtime.h>

#define NEG_SLOPE 0.2f
#define LOG2E 1.44269504f
#define NBUCK 1024          // coarse buckets, 128 nodes each (supports n <= 131072)

typedef __attribute__((ext_vector_type(8))) short bf16x8;
typedef __attribute__((ext_vector_type(4))) float f32x4;

// lrelu(x) = max(x, 0.2x)  (2 VALU ops)
static __device__ __forceinline__ float lrelu(float x) { return fmaxf(x, NEG_SLOPE * x); }

static __device__ __forceinline__ float b2f(unsigned short u) {
    union { unsigned int i; float f; } c; c.i = ((unsigned int)u) << 16; return c.f;
}
static __device__ __forceinline__ unsigned short f2b(float f) {
    union { float f; unsigned int i; } c; c.f = f;
    unsigned int r = c.i + 0x7fff + ((c.i >> 16) & 1);   // RNE
    return (unsigned short)(r >> 16);
}

// ---------------- CSR build: two-level bucket sort ----------------

__global__ __launch_bounds__(256) void bucket_count(const int* __restrict__ dst, int* __restrict__ gcount,
                                                    int ne, int epb) {
    __shared__ int cnt[NBUCK];
    int tid = threadIdx.x;
    for (int i = tid; i < NBUCK; i += 256) cnt[i] = 0;
    __syncthreads();
    int lo = blockIdx.x * epb;
    int hi = min(ne, lo + epb);
    for (int i = lo + tid; i < hi; i += 256) atomicAdd(&cnt[dst[i] >> 7], 1);
    __syncthreads();
    for (int i = tid; i < NBUCK; i += 256) if (cnt[i]) atomicAdd(&gcount[i], cnt[i]);
}

__global__ __launch_bounds__(1024) void bucket_scan(const int* __restrict__ gcount, int* __restrict__ bstart,
                                                    int* __restrict__ gcur) {
    int t = threadIdx.x;
    int v = gcount[t];
    int lane = t & 63, wid = t >> 6;     // 16 waves
    int incl = v;
    #pragma unroll
    for (int off = 1; off < 64; off <<= 1) {
        int u = __shfl_up(incl, off, 64);
        if (lane >= off) incl += u;
    }
    __shared__ int ws[16];
    if (lane == 63) ws[wid] = incl;
    __syncthreads();
    if (t < 16) {
        int s = ws[t];
        #pragma unroll
        for (int off = 1; off < 16; off <<= 1) {
            int u = __shfl_up(s, off, 64);
            if (t >= off) s += u;
        }
        ws[t] = s;
    }
    __syncthreads();
    int excl = incl - v + (wid > 0 ? ws[wid - 1] : 0);
    bstart[t] = excl;
    gcur[t] = excl;
    if (t == 1023) bstart[NBUCK] = excl + v;   // == ne
}

__global__ __launch_bounds__(256) void bucket_place(const int* __restrict__ src, const int* __restrict__ dst,
                                                    int* __restrict__ gcur, unsigned int* __restrict__ gstage,
                                                    int ne, int epb) {
    __shared__ int cnt[NBUCK];
    __shared__ int cur[NBUCK];
    int tid = threadIdx.x;
    for (int i = tid; i < NBUCK; i += 256) cnt[i] = 0;
    __syncthreads();
    int lo = blockIdx.x * epb;
    int hi = min(ne, lo + epb);
    for (int i = lo + tid; i < hi; i += 256) atomicAdd(&cnt[dst[i] >> 7], 1);
    __syncthreads();
    for (int b = tid; b < NBUCK; b += 256) {
        int c = cnt[b];
        cur[b] = c ? atomicAdd(&gcur[b], c) : 0;
    }
    __syncthreads();
    for (int i = lo + tid; i < hi; i += 256) {
        int d = dst[i];
        int b = d >> 7;
        int p = atomicAdd(&cur[b], 1);               // cur holds GLOBAL base
        gstage[p] = (unsigned int)src[i] | (((unsigned int)(d & 127)) << 17);
    }
}

__global__ __launch_bounds__(256) void bucket_csr(const unsigned int* __restrict__ gstage,
                                                  const int* __restrict__ bstart,
                                                  int* __restrict__ rowstart, int* __restrict__ deg,
                                                  int* __restrict__ csrc, int n) {
    int b = blockIdx.x;
    int nodebase = b << 7;
    if (nodebase >= n) return;
    int bs = bstart[b];
    int cntb = bstart[b + 1] - bs;
    __shared__ int hist[128], cur[128], ws[2];
    int tid = threadIdx.x;
    if (tid < 128) hist[tid] = 0;
    __syncthreads();
    for (int i = tid; i < cntb; i += 256) atomicAdd(&hist[(gstage[bs + i] >> 17) & 127], 1);
    __syncthreads();
    int v = 0, incl = 0;
    int lane = tid & 63, wid = tid >> 6;
    if (tid < 128) {
        v = hist[tid];
        incl = v;
        #pragma unroll
        for (int off = 1; off < 64; off <<= 1) {
            int u = __shfl_up(incl, off, 64);
            if (lane >= off) incl += u;
        }
        if (lane == 63) ws[wid] = incl;
    }
    __syncthreads();
    if (tid < 128) {
        int excl = incl - v + (wid == 1 ? ws[0] : 0);
        int node = nodebase + tid;
        if (node < n) { rowstart[node] = bs + excl; deg[node] = v; }
        cur[tid] = excl;
    }
    __syncthreads();
    for (int i = tid; i < cntb; i += 256) {
        unsigned int e = gstage[bs + i];
        int ld = (e >> 17) & 127;
        int p = atomicAdd(&cur[ld], 1);
        csrc[bs + p] = (int)(e & 0x1FFFFu);
    }
}

// ---------------- W1 fragment prep (hi/lo split), one tiny block ----------------

__global__ __launch_bounds__(256) void wprep(const float* __restrict__ W1,
                                             unsigned short* __restrict__ WfH,
                                             unsigned short* __restrict__ WfL) {
    int lane = threadIdx.x & 63, cb = threadIdx.x >> 6;
    int r16 = lane & 15, g4 = lane >> 4;
    for (int kb = 0; kb < 4; ++kb) {
        #pragma unroll
        for (int i = 0; i < 8; ++i) {
            int k = kb * 32 + g4 * 8 + i;
            float v = W1[k * 64 + cb * 16 + r16];
            unsigned short hi = f2b(v);
            unsigned short lo = f2b(v - b2f(hi));
            WfH[((cb * 4 + kb) * 64 + lane) * 8 + i] = hi;
            WfL[((cb * 4 + kb) * 64 + lane) * 8 + i] = lo;
        }
    }
}

// ---------------- Layer 1: h1 = x @ W1 via split-precision bf16 MFMA ----------------
// acc = Ah*Bh + Al*Bh + Ah*Bl (lo*lo dropped) ~= fp32 GEMM.
// es/ed written PRE-SCALED by LOG2E (exp2-domain softmax downstream).

__global__ __launch_bounds__(256) void gemm1(const float* __restrict__ x,
                                             const unsigned short* __restrict__ WfH,
                                             const unsigned short* __restrict__ WfL,
                                             const float* __restrict__ asrc, const float* __restrict__ adst,
                                             unsigned short* __restrict__ h, float* __restrict__ es,
                                             float* __restrict__ ed, int n) {
    __shared__ unsigned short AsH[64 * 128];   // 16 KB
    __shared__ unsigned short AsL[64 * 128];   // 16 KB
    int tid = threadIdx.x, lane = tid & 63, wid = tid >> 6;
    int r16 = lane & 15, g4 = lane >> 4;

    int base = blockIdx.x * 64;
    #pragma unroll
    for (int jj = 0; jj < 8; ++jj) {
        int idx = tid + jj * 256;          // 0..2047
        int r = idx >> 5, c4 = idx & 31;
        int nidx = base + r;
        float4 v = make_float4(0.f, 0.f, 0.f, 0.f);
        if (nidx < n) v = *(const float4*)&x[(size_t)nidx * 128 + c4 * 4];
        unsigned short h0 = f2b(v.x), h1_ = f2b(v.y), h2_ = f2b(v.z), h3_ = f2b(v.w);
        unsigned short l0 = f2b(v.x - b2f(h0)), l1 = f2b(v.y - b2f(h1_));
        unsigned short l2 = f2b(v.z - b2f(h2_)), l3 = f2b(v.w - b2f(h3_));
        int u = c4 >> 1;
        int swz = (((u ^ (r & 15)) << 1) | (c4 & 1)) << 2;  // shorts offset
        *(unsigned long long*)&AsH[r * 128 + swz] =
            (unsigned long long)h0 | ((unsigned long long)h1_ << 16) |
            ((unsigned long long)h2_ << 32) | ((unsigned long long)h3_ << 48);
        *(unsigned long long*)&AsL[r * 128 + swz] =
            (unsigned long long)l0 | ((unsigned long long)l1 << 16) |
            ((unsigned long long)l2 << 32) | ((unsigned long long)l3 << 48);
    }
    __syncthreads();

    bf16x8 afH[4], afL[4];
    int arow = wid * 16 + r16;
    #pragma unroll
    for (int kb = 0; kb < 4; ++kb) {
        int uu = (kb * 4 + g4) ^ r16;
        afH[kb] = *(const bf16x8*)&AsH[arow * 128 + uu * 8];
        afL[kb] = *(const bf16x8*)&AsL[arow * 128 + uu * 8];
    }

    f32x4 acc[4] = {{0.f,0.f,0.f,0.f},{0.f,0.f,0.f,0.f},{0.f,0.f,0.f,0.f},{0.f,0.f,0.f,0.f}};
    #pragma unroll
    for (int cb = 0; cb < 4; ++cb) {
        #pragma unroll
        for (int kb = 0; kb < 4; ++kb) {
            bf16x8 bH = *(const bf16x8*)&WfH[((cb * 4 + kb) * 64 + lane) * 8];
            bf16x8 bL = *(const bf16x8*)&WfL[((cb * 4 + kb) * 64 + lane) * 8];
            acc[cb] = __builtin_amdgcn_mfma_f32_16x16x32_bf16(afH[kb], bH, acc[cb], 0, 0, 0);
            acc[cb] = __builtin_amdgcn_mfma_f32_16x16x32_bf16(afL[kb], bH, acc[cb], 0, 0, 0);
            acc[cb] = __builtin_amdgcn_mfma_f32_16x16x32_bf16(afH[kb], bL, acc[cb], 0, 0, 0);
        }
    }

    // epilogue: D layout col=lane&15, row=(lane>>4)*4+reg
    float ps[4] = {0.f,0.f,0.f,0.f}, pd[4] = {0.f,0.f,0.f,0.f};
    #pragma unroll
    for (int cb = 0; cb < 4; ++cb) {
        int col = cb * 16 + r16;
        float av = asrc[col], dv = adst[col];
        #pragma unroll
        for (int rg = 0; rg < 4; ++rg) {
            int nidx = base + wid * 16 + g4 * 4 + rg;
            float v = acc[cb][rg];
            if (nidx < n) h[(size_t)nidx * 64 + col] = f2b(v);
            ps[rg] = fmaf(v, av, ps[rg]);
            pd[rg] = fmaf(v, dv, pd[rg]);
        }
    }
    #pragma unroll
    for (int off = 8; off >= 1; off >>= 1) {
        #pragma unroll
        for (int rg = 0; rg < 4; ++rg) {
            ps[rg] += __shfl_xor(ps[rg], off, 64);
            pd[rg] += __shfl_xor(pd[rg], off, 64);
        }
    }
    if (r16 == 0) {
        #pragma unroll
        for (int rg = 0; rg < 4; ++rg) {
            int nidx = base + wid * 16 + g4 * 4 + rg;
            if (nidx < n) { es[nidx] = ps[rg] * LOG2E; ed[nidx] = pd[rg] * LOG2E; }
        }
    }
}

// ---------------- Layer 1 aggregation: wave/node, ILP-4 online softmax (exp2 domain) ----------------

__global__ __launch_bounds__(256) void agg1(const unsigned short* __restrict__ h, const float* __restrict__ es,
                                            const float* __restrict__ ed, const float* __restrict__ b1,
                                            const int* __restrict__ rowstart, const int* __restrict__ deg,
                                            const int* __restrict__ csrc, unsigned short* __restrict__ out, int n) {
    int wid = threadIdx.x >> 6, lane = threadIdx.x & 63;
    int node = blockIdx.x * 4 + wid;
    if (node >= n) return;
    float edn = ed[node];
    float m = lrelu(es[node] + edn);    // self-loop (log2 domain)
    float z = 1.0f;
    float acc = b2f(h[(unsigned)(node * 64) + lane]);
    int s0 = rowstart[node], cnt = deg[node];
    int i = 0;
    for (; i + 4 <= cnt; i += 4) {
        int sA = csrc[s0 + i], sB = csrc[s0 + i + 1], sC = csrc[s0 + i + 2], sD = csrc[s0 + i + 3];
        float eA = lrelu(es[sA] + edn), eB = lrelu(es[sB] + edn);
        float eC = lrelu(es[sC] + edn), eD = lrelu(es[sD] + edn);
        float hA = b2f(h[(unsigned)(sA * 64) + lane]);
        float hB = b2f(h[(unsigned)(sB * 64) + lane]);
        float hC = b2f(h[(unsigned)(sC * 64) + lane]);
        float hD = b2f(h[(unsigned)(sD * 64) + lane]);
        float mb = fmaxf(fmaxf(eA, eB), fmaxf(eC, eD));
        if (mb <= m) {                       // wave-uniform
            float wA = __builtin_amdgcn_exp2f(eA - m), wB = __builtin_amdgcn_exp2f(eB - m);
            float wC = __builtin_amdgcn_exp2f(eC - m), wD = __builtin_amdgcn_exp2f(eD - m);
            z += (wA + wB) + (wC + wD);
            acc = fmaf(hA, wA, acc);
            acc = fmaf(hB, wB, acc);
            acc = fmaf(hC, wC, acc);
            acc = fmaf(hD, wD, acc);
        } else {
            float c = __builtin_amdgcn_exp2f(m - mb);
            float wA = __builtin_amdgcn_exp2f(eA - mb), wB = __builtin_amdgcn_exp2f(eB - mb);
            float wC = __builtin_amdgcn_exp2f(eC - mb), wD = __builtin_amdgcn_exp2f(eD - mb);
            z = fmaf(z, c, (wA + wB) + (wC + wD));
            acc = acc * c;
            acc = fmaf(hA, wA, acc);
            acc = fmaf(hB, wB, acc);
            acc = fmaf(hC, wC, acc);
            acc = fmaf(hD, wD, acc);
            m = mb;
        }
    }
    for (; i < cnt; ++i) {
        int s = csrc[s0 + i];
        float e = lrelu(es[s] + edn);
        float hv = b2f(h[(unsigned)(s * 64) + lane]);
        if (e <= m) {
            float w_ = __builtin_amdgcn_exp2f(e - m);
            z += w_;
            acc = fmaf(hv, w_, acc);
        } else {
            float c = __builtin_amdgcn_exp2f(m - e);
            z = fmaf(z, c, 1.0f);
            acc = fmaf(acc, c, hv);
            m = e;
        }
    }
    float o = acc / z + b1[lane];
    out[(unsigned)(node * 64) + lane] = f2b(o > 0.f ? o : 0.f);   // fused ReLU, bf16
}

// ---------------- Layer 2: h2 = hr @ W2, bf16 in/out; W2 column in 64 VGPRs ----------------
// es/ed written PRE-SCALED by LOG2E.

__global__ __launch_bounds__(256) void gemm2(const unsigned short* __restrict__ hin, const float* __restrict__ W2,
                                             const float* __restrict__ asrc, const float* __restrict__ adst,
                                             unsigned short* __restrict__ h2, float* __restrict__ es,
                                             float* __restrict__ ed, int n) {
    __shared__ float xl[16][64];   // 4 KB
    int tid = threadIdx.x;
    int lane = tid & 63, wid = tid >> 6;
    int sub = lane >> 4, j = lane & 15;
    float w2[64];
    #pragma unroll
    for (int k = 0; k < 64; ++k) w2[k] = W2[k * 16 + j];
    int base = blockIdx.x * 16;
    for (int i = tid; i < 16 * 64; i += 256) {
        int r = i >> 6, c = i & 63;
        int nidx = base + r;
        xl[r][c] = (nidx < n) ? b2f(hin[(unsigned)(nidx * 64) + c]) : 0.f;
    }
    __syncthreads();
    int r = wid * 4 + sub;
    int nidx = base + r;
    if (nidx < n) {
        float acc = 0.f;
        #pragma unroll
        for (int kk = 0; kk < 16; ++kk) {
            float4 xv = *(const float4*)&xl[r][kk * 4];
            acc = fmaf(xv.x, w2[4 * kk + 0], acc);
            acc = fmaf(xv.y, w2[4 * kk + 1], acc);
            acc = fmaf(xv.z, w2[4 * kk + 2], acc);
            acc = fmaf(xv.w, w2[4 * kk + 3], acc);
        }
        h2[(unsigned)(nidx * 16) + j] = f2b(acc);
        float s = acc * asrc[j], d = acc * adst[j];
        #pragma unroll
        for (int off = 8; off >= 1; off >>= 1) {
            s += __shfl_xor(s, off, 64);
            d += __shfl_xor(d, off, 64);
        }
        if (j == 0) { es[nidx] = s * LOG2E; ed[nidx] = d * LOG2E; }
    }
}

// ---------------- Layer 2 aggregation + bias + log_softmax (exp2 domain) ----------------

__global__ __launch_bounds__(256) void agg2(const unsigned short* __restrict__ h, const float* __restrict__ es,
                                            const float* __restrict__ ed, const float* __restrict__ b2,
                                            const int* __restrict__ rowstart, const int* __restrict__ deg,
                                            const int* __restrict__ csrc, float* __restrict__ out, int n) {
    int wid = threadIdx.x >> 6, lane = threadIdx.x & 63;
    int node = blockIdx.x * 4 + wid;
    if (node >= n) return;
    int sub = lane >> 4, j = lane & 15;
    float edn = ed[node];
    int s0 = rowstart[node], cnt = deg[node];
    int total = cnt + 1;                       // virtual edge 0 = self-loop
    float m = -1e30f, z = 0.f, acc = 0.f;
    for (int i = sub; i < total; i += 4) {
        int s = (i == 0) ? node : csrc[s0 + i - 1];
        float e = lrelu(es[s] + edn);
        float hv = b2f(h[(unsigned)(s * 16) + j]);
        if (e <= m) {
            float w_ = __builtin_amdgcn_exp2f(e - m);
            z += w_;
            acc = fmaf(hv, w_, acc);
        } else {
            float c = __builtin_amdgcn_exp2f(m - e);
            z = fmaf(z, c, 1.0f);
            acc = fmaf(acc, c, hv);
            m = e;
        }
    }
    #pragma unroll
    for (int off = 16; off <= 32; off <<= 1) {
        float mo = __shfl_xor(m, off, 64);
        float zo = __shfl_xor(z, off, 64);
        float ao = __shfl_xor(acc, off, 64);
        float mn = fmaxf(m, mo);
        float c0 = __builtin_amdgcn_exp2f(m - mn), c1 = __builtin_amdgcn_exp2f(mo - mn);
        z = z * c0 + zo * c1;
        acc = acc * c0 + ao * c1;
        m = mn;
    }
    float val = acc / z + b2[j];
    float mx = val;
    #pragma unroll
    for (int off = 8; off >= 1; off >>= 1) mx = fmaxf(mx, __shfl_xor(mx, off, 64));
    float ex = __expf(val - mx);
    float se = ex;
    #pragma unroll
    for (int off = 8; off >= 1; off >>= 1) se += __shfl_xor(se, off, 64);
    float res = val - mx - __logf(se);
    if (sub == 0) out[(unsigned)(node * 16) + j] = res;
}

// ---------------- launch ----------------

extern "C" void kernel_launch(void* const* d_in, const int* in_sizes, int n_in,
                              void* d_out, int out_size, void* d_ws, size_t ws_size,
                              hipStream_t stream) {
    const float* x   = (const float*)d_in[0];
    const int*   ei  = (const int*)d_in[1];
    const float* W1  = (const float*)d_in[2];
    const float* as1 = (const float*)d_in[3];
    const float* ad1 = (const float*)d_in[4];
    const float* b1  = (const float*)d_in[5];
    const float* W2  = (const float*)d_in[6];
    const float* as2 = (const float*)d_in[7];
    const float* ad2 = (const float*)d_in[8];
    const float* b2  = (const float*)d_in[9];
    int n  = in_sizes[0] / 128;
    int ne = in_sizes[1] / 2;
    const int* srcv = ei;
    const int* dstv = ei + ne;

    char* ws = (char*)d_ws;
    size_t off = 0;
    auto alloc = [&](size_t bytes) -> void* {
        void* p = ws + off;
        off = (off + bytes + 255) & ~(size_t)255;
        return p;
    };
    unsigned short* h1 = (unsigned short*)alloc((size_t)n * 64 * 2);
    unsigned short* hr = (unsigned short*)alloc((size_t)n * 64 * 2);
    unsigned short* h2 = (unsigned short*)alloc((size_t)n * 16 * 2);
    float* es1  = (float*)alloc((size_t)n * 4);
    float* ed1  = (float*)alloc((size_t)n * 4);
    float* es2  = (float*)alloc((size_t)n * 4);
    float* ed2  = (float*)alloc((size_t)n * 4);
    unsigned short* WfH = (unsigned short*)alloc(16 * 64 * 8 * 2);
    unsigned short* WfL = (unsigned short*)alloc(16 * 64 * 8 * 2);
    int* deg      = (int*)alloc((size_t)n * 4);
    int* rowstart = (int*)alloc((size_t)n * 4);
    int* bcount   = (int*)alloc((size_t)NBUCK * 4);
    int* bstart   = (int*)alloc((size_t)(NBUCK + 1) * 4);
    int* gcur     = (int*)alloc((size_t)NBUCK * 4);
    unsigned int* gstage = (unsigned int*)alloc((size_t)ne * 4);
    int* csrc     = (int*)alloc((size_t)ne * 4);

    int nblk = 256;
    int epb = (ne + nblk - 1) / nblk;
    hipMemsetAsync(bcount, 0, (size_t)NBUCK * 4, stream);
    bucket_count<<<nblk, 256, 0, stream>>>(dstv, bcount, ne, epb);
    bucket_scan<<<1, 1024, 0, stream>>>(bcount, bstart, gcur);
    bucket_place<<<nblk, 256, 0, stream>>>(srcv, dstv, gcur, gstage, ne, epb);
    bucket_csr<<<NBUCK, 256, 0, stream>>>(gstage, bstart, rowstart, deg, csrc, n);

    wprep<<<1, 256, 0, stream>>>(W1, WfH, WfL);
    gemm1<<<(n + 63) / 64, 256, 0, stream>>>(x, WfH, WfL, as1, ad1, h1, es1, ed1, n);
    agg1<<<(n + 3) / 4, 256, 0, stream>>>(h1, es1, ed1, b1, rowstart, deg, csrc, hr, n);

    gemm2<<<(n + 15) / 16, 256, 0, stream>>>(hr, W2, as2, ad2, h2, es2, ed2, n);
    agg2<<<(n + 3) / 4, 256, 0, stream>>>(h2, es2, ed2, b2, rowstart, deg, csrc, (float*)d_out, n);
}